// Round 9
// baseline (215.929 us; speedup 1.0000x reference)
//
#include <hip/hip_runtime.h>
#include <hip/hip_bf16.h>
#include <stdint.h>

// ---------------- problem constants ----------------
#define N_NODES 16384
#define D_IN    256
#define D_OUT   256
#define K_SAMP  10
#define HALF_FLAT (1u << 27)

#define NPB 32          // nodes per block
#define NPW 4           // nodes per wave (8 waves)

// JAX PRNG mode: 1 = jax_threefry_partitionable (verified correct R3-R8).
#define JAX_PARTITIONABLE 1

typedef __attribute__((ext_vector_type(4))) float  f32x4;
typedef __attribute__((ext_vector_type(8))) short  bf16x8;
typedef __attribute__((ext_vector_type(4))) int    i32x4;

__device__ __forceinline__ uint32_t rotl32(uint32_t x, int r) {
    return (x << r) | (x >> (32 - r));
}

// Exact replica of jax threefry2x32 noise bits for flat index i = r*16384 + c, key (0,42).
__device__ __forceinline__ uint32_t jax_noise_bits(uint32_t r, uint32_t c) {
    const uint32_t i  = (r << 14) | c;
    const uint32_t k0 = 0u, k1 = 42u;
    const uint32_t k2 = 42u ^ 0x1BD11BDAu;
    uint32_t x0, x1;
#if JAX_PARTITIONABLE
    x0 = 0u;
    x1 = i;
#else
    const bool lo = (i < HALF_FLAT);
    x0 = lo ? i : (i - HALF_FLAT);
    x1 = lo ? (i + HALF_FLAT) : i;
#endif
    x0 += k0; x1 += k1;
#define TFR4(a,b,cc,d) \
    x0 += x1; x1 = rotl32(x1,a);  x1 ^= x0; \
    x0 += x1; x1 = rotl32(x1,b);  x1 ^= x0; \
    x0 += x1; x1 = rotl32(x1,cc); x1 ^= x0; \
    x0 += x1; x1 = rotl32(x1,d);  x1 ^= x0;
    TFR4(13,15,26,6);   x0 += k1; x1 += k2 + 1u;
    TFR4(17,29,16,24);  x0 += k2; x1 += k0 + 2u;
    TFR4(13,15,26,6);   x0 += k0; x1 += k1 + 3u;
    TFR4(17,29,16,24);  x0 += k1; x1 += k2 + 4u;
    TFR4(13,15,26,6);   x0 += k2; x1 += k0 + 5u;
#undef TFR4
#if JAX_PARTITIONABLE
    return x0 ^ x1;
#else
    return (i < HALF_FLAT) ? x0 : x1;
#endif
}

__device__ __forceinline__ unsigned short f2bfbits(float f) {
    __hip_bfloat16 h = __float2bfloat16(f);
    return *(unsigned short*)&h;
}

// ---------------- kernel W: convert W (f32 [256][512]) → Wb bf16 ----------------
// Separate kernel so Wb is globally visible before k_fused (kernel boundary = fence).
__global__ __launch_bounds__(256) void k_convw(const float* __restrict__ W,
                                               unsigned short* __restrict__ Wb)
{
    int i = (blockIdx.x * 256 + threadIdx.x) * 4;
    f32x4 v = *(const f32x4*)(W + i);
    ushort4 u;
    u.x = f2bfbits(v[0]); u.y = f2bfbits(v[1]);
    u.z = f2bfbits(v[2]); u.w = f2bfbits(v[3]);
    *(ushort4*)(Wb + i) = u;
}

// ---------------- fused kernel: sample+aggregate (h in LDS) + MFMA GEMM + relu ----------
// 512 blocks x 512 threads (8 waves). Block owns 32 nodes; wave owns 4 (sequential).
// Phase A (per wave, no barriers): nt-stream adjacency row, ballot-compact nonzero cols,
//   dense threefry, register top-10 (batched masked gathers), write h row (bf16,
//   XOR-swizzled) into LDS hS.
// Phase B (after one __syncthreads): GEMM M=32,N=256,K=512. A = hS (LDS-resident),
//   B = Wb streamed through Bs in BK=64 chunks with register prefetch of the next chunk.
//   MFMA conventions identical to the R6-verified kernel. Bias+ReLU, f32 out.
__global__ __launch_bounds__(512, 4) void k_fused(
    const float* __restrict__ x, const float* __restrict__ adj,
    const unsigned short* __restrict__ Wb, const float* __restrict__ bias,
    float* __restrict__ out)
{
    __shared__ short hS[NPB * 512];        // 32 KB  h tile, rows XOR-swizzled
    __shared__ short Bs[256 * 64];         // 32 KB  Wb chunk (rows XOR-swizzled)
    unsigned short* candc = (unsigned short*)Bs;   // [8][128] aliased (phase A only)

    const int t    = threadIdx.x;
    const int lane = t & 63;
    const int w    = t >> 6;

    // ================= Phase A: sampling =================
    for (int i = 0; i < NPW; ++i) {
        const int lrow = w * NPW + i;                  // 0..31
        const int r    = blockIdx.x * NPB + lrow;

        // ---- stream + compact (nt loads, integer fast path: adj is exactly 0.0/1.0) ----
        const i32x4* rowp = (const i32x4*)(adj + (size_t)r * N_NODES);
        int nc = 0;                                    // wave-uniform candidate count
        #pragma unroll 8
        for (int it = 0; it < 64; ++it) {
            i32x4 v = __builtin_nontemporal_load(rowp + it * 64 + lane);
            uint32_t any = (uint32_t)v[0] | (uint32_t)v[1] | (uint32_t)v[2] | (uint32_t)v[3];
            if (__ballot(any != 0u)) {
                int cb = (it * 64 + lane) * 4;
                #pragma unroll
                for (int j = 0; j < 4; ++j) {
                    unsigned long long mask = __ballot(v[j] != 0);
                    if (mask) {
                        if (v[j] != 0) {
                            int below = __builtin_amdgcn_mbcnt_hi(
                                (uint32_t)(mask >> 32),
                                __builtin_amdgcn_mbcnt_lo((uint32_t)mask, 0));
                            int slot = nc + below;
                            if (slot < 128) candc[w * 128 + slot] = (unsigned short)(cb + j);
                        }
                        nc += __popcll(mask);
                    }
                }
            }
        }
        if (nc > 128) nc = 128;                        // P(deg>128) ~ 0 (17 sigma)

        // ---- dense threefry: keys for candidates lane and lane+64 ----
        // (within-wave LDS write->read ordering handled by lgkmcnt; no barrier needed)
        unsigned long long k0 = 0ull, k1 = 0ull;
        if (lane < nc) {
            uint32_t c   = candc[w * 128 + lane];
            uint32_t u23 = jax_noise_bits((uint32_t)r, c) >> 9;  // monotone with uniform
            k0 = ((((unsigned long long)u23) << 14) | (unsigned long long)(16383u - c)) + 1ull;
        }
        if (64 + lane < nc) {
            uint32_t c   = candc[w * 128 + 64 + lane];
            uint32_t u23 = jax_noise_bits((uint32_t)r, c) >> 9;
            k1 = ((((unsigned long long)u23) << 14) | (unsigned long long)(16383u - c)) + 1ull;
        }

        // ---- top-10 (register space); collect cols, then batched masked gathers ----
        const int m = nc < K_SAMP ? nc : K_SAMP;
        int cols[K_SAMP];
        #pragma unroll
        for (int s = 0; s < K_SAMP; ++s) {
            unsigned long long my = k0 > k1 ? k0 : k1;
            #pragma unroll
            for (int o = 1; o < 64; o <<= 1) {
                unsigned long long other = __shfl_xor(my, o);
                if (other > my) my = other;
            }
            if (k0 == my) k0 = 0ull; else if (k1 == my) k1 = 0ull;
            // my==0 (s>=m) -> col=0: valid address, masked by weight below
            cols[s] = 16383 - (int)((my - 1ull) & 0x3FFFull);
        }
        f32x4 acc = {0.f, 0.f, 0.f, 0.f};
        #pragma unroll
        for (int s = 0; s < K_SAMP; ++s) {
            const float wt = (s < m) ? 1.0f : 0.0f;
            f32x4 xv = *(const f32x4*)(x + (size_t)cols[s] * D_IN + lane * 4);
            acc += wt * xv;
        }
        const float inv = (m > 0) ? 1.0f / (float)m : 0.0f;

        // ---- write h row (bf16) into LDS, swizzled: byte ^= (row&7)<<4 ----
        f32x4 sv = *(const f32x4*)(x + (size_t)r * D_IN + lane * 4);
        ushort4 us, ua;
        us.x = f2bfbits(sv[0]);        us.y = f2bfbits(sv[1]);
        us.z = f2bfbits(sv[2]);        us.w = f2bfbits(sv[3]);
        ua.x = f2bfbits(acc[0] * inv); ua.y = f2bfbits(acc[1] * inv);
        ua.z = f2bfbits(acc[2] * inv); ua.w = f2bfbits(acc[3] * inv);
        const int swz = (lrow & 7) << 4;
        *(ushort4*)((char*)hS + ((lrow * 1024 + lane * 8) ^ swz))       = us;   // self
        *(ushort4*)((char*)hS + ((lrow * 1024 + 512 + lane * 8) ^ swz)) = ua;   // agg
    }

    __syncthreads();   // h tile complete; candc dead; Bs may now be used

    // ================= Phase B: GEMM =================
    const int wm = w >> 2;         // 0..1  (16 rows each)
    const int wn = w & 3;          // 0..3  (64 cols each)
    const int lr = lane & 15;
    const int lk = lane >> 4;

    f32x4 acc[4] = {};             // 4 n-frags x 4 f32

    // Bs staging geometry: 2048 x 16B, 4 per thread
    int srow[4], sc16[4], sba[4];
    #pragma unroll
    for (int i2 = 0; i2 < 4; ++i2) {
        int q = t + i2 * 512;
        srow[i2] = q >> 3; sc16[i2] = q & 7;
        sba[i2]  = (srow[i2] * 128 + sc16[i2] * 16) ^ ((srow[i2] & 7) << 4);
    }

    // prologue: load chunk 0 into regs
    i32x4 breg[4];
    #pragma unroll
    for (int i2 = 0; i2 < 4; ++i2)
        breg[i2] = *(const i32x4*)(Wb + (size_t)srow[i2] * 512 + sc16[i2] * 8);

    for (int cc = 0; cc < 8; ++cc) {
        // ds_write staged regs (waits vmcnt automatically)
        #pragma unroll
        for (int i2 = 0; i2 < 4; ++i2)
            *(i32x4*)((char*)Bs + sba[i2]) = breg[i2];
        __syncthreads();

        if (cc < 7) {
            const int kb = (cc + 1) * 64;
            #pragma unroll
            for (int i2 = 0; i2 < 4; ++i2)
                breg[i2] = *(const i32x4*)(Wb + (size_t)srow[i2] * 512 + kb + sc16[i2] * 8);
        }

        #pragma unroll
        for (int kk = 0; kk < 64; kk += 32) {
            // A fragment from hS: row = wm*16+lr, k-bytes within 1024-B row
            const int arow = wm * 16 + lr;
            const int aba  = (arow * 1024 + cc * 128 + kk * 2 + lk * 16) ^ ((arow & 7) << 4);
            bf16x8 af = *(const bf16x8*)((const char*)hS + aba);
            #pragma unroll
            for (int ni = 0; ni < 4; ++ni) {
                const int n  = wn * 64 + ni * 16 + lr;
                const int bb = (n * 128 + kk * 2 + lk * 16) ^ ((n & 7) << 4);
                bf16x8 bf = *(const bf16x8*)((const char*)Bs + bb);
                acc[ni] = __builtin_amdgcn_mfma_f32_16x16x32_bf16(af, bf, acc[ni], 0, 0, 0);
            }
        }
        __syncthreads();
    }

    // epilogue: C/D layout col=lane&15, row=(lane>>4)*4+j  [verified m89]
    #pragma unroll
    for (int ni = 0; ni < 4; ++ni) {
        const int col = wn * 64 + ni * 16 + lr;
        const float bv = bias[col];
        #pragma unroll
        for (int j = 0; j < 4; ++j) {
            const int rowg = blockIdx.x * NPB + wm * 16 + lk * 4 + j;
            float v = acc[ni][j] + bv;
            v = v > 0.0f ? v : 0.0f;
            __builtin_nontemporal_store(v, out + (size_t)rowg * D_OUT + col);
        }
    }
}

// ---------------- launch ----------------
extern "C" void kernel_launch(void* const* d_in, const int* in_sizes, int n_in,
                              void* d_out, int out_size, void* d_ws, size_t ws_size,
                              hipStream_t stream) {
    (void)in_sizes; (void)n_in; (void)out_size; (void)ws_size;
    const float* x   = (const float*)d_in[0];
    const float* adj = (const float*)d_in[1];
    const float* W   = (const float*)d_in[2];
    const float* b   = (const float*)d_in[3];

    unsigned short* Wb = (unsigned short*)d_ws;    // 256 KB bf16 W
    float* out = (float*)d_out;

    hipLaunchKernelGGL(k_convw, dim3(128), dim3(256), 0, stream, W, Wb);
    hipLaunchKernelGGL(k_fused, dim3(N_NODES / NPB), dim3(512), 0, stream,
                       x, adj, Wb, b, out);
}